// Round 5
// baseline (6326.017 us; speedup 1.0000x reference)
//
#include <hip/hip_runtime.h>

typedef __bf16 bf16;
typedef __attribute__((ext_vector_type(8))) __bf16 bf16x8;
typedef __attribute__((ext_vector_type(4))) __bf16 bf16x4;
typedef __attribute__((ext_vector_type(4))) float f32x4;
typedef __attribute__((ext_vector_type(8))) short s16x8;

__device__ __forceinline__ f32x4 mfma16(s16x8 a, s16x8 b, f32x4 c) {
  return __builtin_amdgcn_mfma_f32_16x16x32_bf16(a, b, c, 0, 0, 0);
}

// ---------------------------------------------------------------------------
// split_f32: X f32 [n4*4] -> hi/lo bf16 planes (same layout).
// hi = bf16(x); lo = bf16(x - hi). Memory-bound, grid-stride.
// ---------------------------------------------------------------------------
__global__ __launch_bounds__(256) void split_f32(const float* __restrict__ X,
                                                 bf16* __restrict__ Xh,
                                                 bf16* __restrict__ Xl,
                                                 int n4) {
  int i = blockIdx.x * 256 + threadIdx.x;
  int stride = gridDim.x * 256;
  for (; i < n4; i += stride) {
    f32x4 v = *(const f32x4*)&X[(size_t)i * 4];
    bf16x4 h, l;
#pragma unroll
    for (int j = 0; j < 4; ++j) {
      bf16 hi = (bf16)v[j];
      h[j] = hi;
      l[j] = (bf16)(v[j] - (float)hi);
    }
    *(bf16x4*)&Xh[(size_t)i * 4] = h;
    *(bf16x4*)&Xl[(size_t)i * 4] = l;
  }
}

// ---------------------------------------------------------------------------
// wtrans: W[1024][1024] f32 ([k][n]) -> WT_hi/WT_lo bf16 [n][k]. (verified)
// ---------------------------------------------------------------------------
__global__ __launch_bounds__(256) void wtrans(const float* __restrict__ W,
                                              bf16* __restrict__ Th,
                                              bf16* __restrict__ Tl) {
  __shared__ float Ts[64][65];
  int tid = threadIdx.x;
  int k0 = (blockIdx.x & 15) << 6, n0 = (blockIdx.x >> 4) << 6;
  int r = tid >> 2, c0 = (tid & 3) << 4;
#pragma unroll
  for (int j = 0; j < 16; j += 4) {
    f32x4 v = *(const f32x4*)&W[(size_t)(k0 + r) * 1024 + n0 + c0 + j];
#pragma unroll
    for (int q = 0; q < 4; ++q) Ts[r][c0 + j + q] = v[q];
  }
  __syncthreads();
  int nl = tid & 63, kq = (tid >> 6) << 4;
#pragma unroll
  for (int j = 0; j < 16; ++j) {
    float v = Ts[kq + j][nl];
    bf16 hi = (bf16)v;
    bf16 lo = (bf16)(v - (float)hi);
    Th[(size_t)(n0 + nl) * 1024 + k0 + kq + j] = hi;
    Tl[(size_t)(n0 + nl) * 1024 + k0 + kq + j] = lo;
  }
}

// ---------------------------------------------------------------------------
// vtrans: Vpf f32 [16384][1024] -> VT hi/lo bf16 [1024][16384] (d-major).
// 64x64 LDS tile; writes are 128 B contiguous per 8-lane group.
// ---------------------------------------------------------------------------
__global__ __launch_bounds__(256) void vtrans(const float* __restrict__ V,
                                              bf16* __restrict__ Th,
                                              bf16* __restrict__ Tl) {
  __shared__ float Ts[64][65];
  int tid = threadIdx.x;
  int s0 = (blockIdx.x & 255) << 6;
  int d0 = (blockIdx.x >> 8) << 6;
  int r = tid >> 2, c0 = (tid & 3) << 4;
#pragma unroll
  for (int j = 0; j < 16; j += 4) {
    f32x4 v = *(const f32x4*)&V[(size_t)(s0 + r) * 1024 + d0 + c0 + j];
#pragma unroll
    for (int q = 0; q < 4; ++q) Ts[r][c0 + j + q] = v[q];
  }
  __syncthreads();
  int d = tid >> 3, sc = (tid & 7) << 3;
#pragma unroll
  for (int pass = 0; pass < 2; ++pass) {
    int dd = d + (pass << 5);
    union { bf16 b[8]; s16x8 v; } hb, lb;
#pragma unroll
    for (int j = 0; j < 8; ++j) {
      float x = Ts[sc + j][dd];
      bf16 hi = (bf16)x;
      hb.b[j] = hi;
      lb.b[j] = (bf16)(x - (float)hi);
    }
    size_t o = (size_t)(d0 + dd) * 16384 + s0 + sc;
    *(s16x8*)&Th[o] = hb.v;
    *(s16x8*)&Tl[o] = lb.v;
  }
}

// ---------------------------------------------------------------------------
// gemm_mfma v2: out = A @ W + bias (+seg_emb if mode==1), A pre-split into
// hi/lo bf16 planes [M][1024], W pre-transposed hi/lo [n][k].
// NO LDS, NO barriers: all fragments straight from global (L2-hot; 16 lanes
// x 16 B = full cache lines). 128x128 tile, 4 waves (2x2 of 64x64),
// 16x16x32 MFMA, 3-term hi/lo per k-step. Waves free-run; compiler
// software-pipelines loads across k-steps (no vmcnt(0) drains).
// C/D layout (HW-verified): col = lane&15, row = (lane>>4)*4 + reg.
// OUTM: 0 -> f32 out; 2 -> dual hi/lo bf16 planes.
// ---------------------------------------------------------------------------
template <int OUTM>
__global__ __launch_bounds__(256, 2) void gemm_mfma(
    const bf16* __restrict__ Ah, const bf16* __restrict__ Al,
    const bf16* __restrict__ WTh, const bf16* __restrict__ WTl,
    const float* __restrict__ bias, float* __restrict__ outF,
    bf16* __restrict__ outH, bf16* __restrict__ outL, int M, int mode,
    const int* __restrict__ segids, const float* __restrict__ segemb) {
  int tid = threadIdx.x;
  int lane = tid & 63, w = tid >> 6;
  int wm = (w & 1) << 6, wn = (w >> 1) << 6;
  int lrow = lane & 15, lkb = (lane >> 4) << 3;
  int bn = blockIdx.x & 7, bm = blockIdx.x >> 3;  // bn-fast: W panels L2-hot
  int m0 = bm << 7, n0 = bn << 7;

  f32x4 acc[4][4];
#pragma unroll
  for (int i = 0; i < 4; i++)
#pragma unroll
    for (int j = 0; j < 4; j++) {
      acc[i][j][0] = 0.f; acc[i][j][1] = 0.f;
      acc[i][j][2] = 0.f; acc[i][j][3] = 0.f;
    }

  const bf16* aph = Ah + (size_t)(m0 + wm + lrow) * 1024 + lkb;
  const bf16* apl = Al + (size_t)(m0 + wm + lrow) * 1024 + lkb;
  const bf16* bph = WTh + (size_t)(n0 + wn + lrow) * 1024 + lkb;
  const bf16* bpl = WTl + (size_t)(n0 + wn + lrow) * 1024 + lkb;

  for (int k0 = 0; k0 < 1024; k0 += 32) {
    s16x8 bh[4], ah[4], xl[4];
#pragma unroll
    for (int nt = 0; nt < 4; ++nt) bh[nt] = *(const s16x8*)(bph + nt * 16384 + k0);
#pragma unroll
    for (int mt = 0; mt < 4; ++mt) ah[mt] = *(const s16x8*)(aph + mt * 16384 + k0);
#pragma unroll
    for (int mt = 0; mt < 4; ++mt)
#pragma unroll
      for (int nt = 0; nt < 4; ++nt)
        acc[mt][nt] = mfma16(ah[mt], bh[nt], acc[mt][nt]);
    // lo(A) * hi(W)
#pragma unroll
    for (int mt = 0; mt < 4; ++mt) xl[mt] = *(const s16x8*)(apl + mt * 16384 + k0);
#pragma unroll
    for (int mt = 0; mt < 4; ++mt)
#pragma unroll
      for (int nt = 0; nt < 4; ++nt)
        acc[mt][nt] = mfma16(xl[mt], bh[nt], acc[mt][nt]);
    // hi(A) * lo(W)
#pragma unroll
    for (int nt = 0; nt < 4; ++nt) xl[nt] = *(const s16x8*)(bpl + nt * 16384 + k0);
#pragma unroll
    for (int mt = 0; mt < 4; ++mt)
#pragma unroll
      for (int nt = 0; nt < 4; ++nt)
        acc[mt][nt] = mfma16(ah[mt], xl[nt], acc[mt][nt]);
  }

  int rbase = (lane >> 4) << 2;
#pragma unroll
  for (int mt = 0; mt < 4; ++mt) {
#pragma unroll
    for (int r = 0; r < 4; ++r) {
      int m = m0 + wm + mt * 16 + rbase + r;
      int seg = (mode == 1) ? segids[m] : 0;
#pragma unroll
      for (int nt = 0; nt < 4; ++nt) {
        int n = n0 + wn + nt * 16 + lrow;
        float v = acc[mt][nt][r] + bias[n];
        if (mode == 1) v += segemb[(size_t)seg * 1024 + n];
        size_t o = (size_t)m * 1024 + n;
        if constexpr (OUTM == 0) {
          outF[o] = v;
        } else {
          bf16 hi = (bf16)v;
          outH[o] = hi;
          outL[o] = (bf16)(v - (float)hi);
        }
      }
    }
  }
}

// ---------------------------------------------------------------------------
// qk_mfma: Sc[bg*TC + t-tBase][4096] = mask ? (Q[t].K[s])*0.125 : -1e9.
// No LDS; fragments straight from hi/lo planes. (verified round 4)
// ---------------------------------------------------------------------------
__global__ __launch_bounds__(256, 3) void qk_mfma(
    const bf16* __restrict__ Qh, const bf16* __restrict__ Ql,
    const bf16* __restrict__ Kh, const bf16* __restrict__ Kl,
    const int* __restrict__ mask, float* __restrict__ Sc,
    int G, int TC, int h0, int tBase) {
  int tid = threadIdx.x;
  int lane = tid & 63, w = tid >> 6;
  int wm = (w & 1) << 6, wn = (w >> 1) << 6;
  int lrow = lane & 15, lkb = (lane >> 4) << 3;
  int tiles_t = TC >> 7;
  int bid = blockIdx.x;
  int rest = bid % (tiles_t * 32);
  int bg = bid / (tiles_t * 32);
  int tm = rest % tiles_t, sn = rest / tiles_t;
  int b = bg / G, g = bg % G, h = h0 + g;
  int t0 = tBase + (tm << 7), s0 = sn << 7;
  int tl0 = t0 - tBase + bg * TC;

  f32x4 acc[4][4];
#pragma unroll
  for (int i = 0; i < 4; i++)
#pragma unroll
    for (int j = 0; j < 4; j++) {
      acc[i][j][0] = 0.f; acc[i][j][1] = 0.f;
      acc[i][j][2] = 0.f; acc[i][j][3] = 0.f;
    }

#pragma unroll
  for (int ks = 0; ks < 2; ++ks) {
    s16x8 ah[4], al[4], bh[4], bl[4];
#pragma unroll
    for (int mt = 0; mt < 4; ++mt) {
      size_t ro = (((size_t)((b << 9) + t0 + wm + mt * 16 + lrow)) << 10) +
                  (h << 6) + ks * 32 + lkb;
      ah[mt] = *(const s16x8*)&Qh[ro];
      al[mt] = *(const s16x8*)&Ql[ro];
    }
#pragma unroll
    for (int nt = 0; nt < 4; ++nt) {
      size_t ro = (((size_t)((b << 12) + s0 + wn + nt * 16 + lrow)) << 10) +
                  (h << 6) + ks * 32 + lkb;
      bh[nt] = *(const s16x8*)&Kh[ro];
      bl[nt] = *(const s16x8*)&Kl[ro];
    }
#pragma unroll
    for (int mt = 0; mt < 4; ++mt)
#pragma unroll
      for (int nt = 0; nt < 4; ++nt) {
        acc[mt][nt] = mfma16(ah[mt], bh[nt], acc[mt][nt]);
        acc[mt][nt] = mfma16(ah[mt], bl[nt], acc[mt][nt]);
        acc[mt][nt] = mfma16(al[mt], bh[nt], acc[mt][nt]);
      }
  }

  const int* mrow = mask + (b << 12) + s0 + wn;
  bool mk[4];
#pragma unroll
  for (int nt = 0; nt < 4; ++nt) mk[nt] = (mrow[nt * 16 + lrow] != 0);

  int rbase = (lane >> 4) << 2;
#pragma unroll
  for (int mt = 0; mt < 4; ++mt) {
#pragma unroll
    for (int r = 0; r < 4; ++r) {
      size_t row = (((size_t)(tl0 + wm + mt * 16 + rbase + r)) << 12) + s0 + wn;
#pragma unroll
      for (int nt = 0; nt < 4; ++nt) {
        Sc[row + nt * 16 + lrow] = mk[nt] ? acc[mt][nt][r] * 0.125f : -1.0e9f;
      }
    }
  }
}

// ---------------------------------------------------------------------------
// Softmax (exact: max, __expf, sum) + provenance; all-register row.
// PMODE 1: normalized P written bf16 to Pb.
// ---------------------------------------------------------------------------
template <int PMODE>
__global__ __launch_bounds__(256, 2) void softmax_prov(
    float* __restrict__ Sc, bf16* __restrict__ Pb, float* __restrict__ prov,
    int G, int TC, int h0, int tBase) {
  __shared__ float red[4];

  int tid = threadIdx.x, wv = tid >> 6;
  int bid = blockIdx.x;
  int b = bid / TC, tl = bid % TC;
  int t = tBase + tl;

  float pacc[16];
#pragma unroll
  for (int i = 0; i < 16; i++) pacc[i] = 0.f;

  for (int g = 0; g < G; ++g) {
    size_t base = ((size_t)((b * G + g) * TC + tl)) << 12;
    f32x4 v[4];
    float mx = -3.0e38f;
#pragma unroll
    for (int it = 0; it < 4; ++it) {
      int s = (tid << 2) + (it << 10);
      v[it] = *(const f32x4*)&Sc[base + s];
      mx = fmaxf(fmaxf(fmaxf(mx, v[it][0]), v[it][1]), fmaxf(v[it][2], v[it][3]));
    }
#pragma unroll
    for (int o = 32; o; o >>= 1) mx = fmaxf(mx, __shfl_xor(mx, o));
    if ((tid & 63) == 0) red[wv] = mx;
    __syncthreads();
    float m = fmaxf(fmaxf(red[0], red[1]), fmaxf(red[2], red[3]));
    __syncthreads();

    float sm = 0.f;
#pragma unroll
    for (int it = 0; it < 4; ++it) {
      f32x4 p;
      p[0] = __expf(v[it][0] - m);
      p[1] = __expf(v[it][1] - m);
      p[2] = __expf(v[it][2] - m);
      p[3] = __expf(v[it][3] - m);
      v[it] = p;
      sm += (p[0] + p[1]) + (p[2] + p[3]);
    }
#pragma unroll
    for (int o = 32; o; o >>= 1) sm += __shfl_xor(sm, o);
    if ((tid & 63) == 0) red[wv] = sm;
    __syncthreads();
    float il = 1.0f / (((red[0] + red[1]) + (red[2] + red[3])));
    __syncthreads();

#pragma unroll
    for (int it = 0; it < 4; ++it) {
      int s = (tid << 2) + (it << 10);
      f32x4 pn;
      pn[0] = v[it][0] * il;
      pn[1] = v[it][1] * il;
      pn[2] = v[it][2] * il;
      pn[3] = v[it][3] * il;
      if constexpr (PMODE == 1) {
        bf16x4 pb;
        pb[0] = (bf16)pn[0]; pb[1] = (bf16)pn[1];
        pb[2] = (bf16)pn[2]; pb[3] = (bf16)pn[3];
        *(bf16x4*)&Pb[base + s] = pb;
      } else {
        *(f32x4*)&Sc[base + s] = pn;
      }
      pacc[it * 4 + 0] += pn[0] * 0.0625f;
      pacc[it * 4 + 1] += pn[1] * 0.0625f;
      pacc[it * 4 + 2] += pn[2] * 0.0625f;
      pacc[it * 4 + 3] += pn[3] * 0.0625f;
    }
  }

  size_t pbase = (((size_t)((b << 9) + t)) << 12);
#pragma unroll
  for (int it = 0; it < 4; ++it) {
    int s = (tid << 2) + (it << 10);
    f32x4 pa;
    pa[0] = pacc[it * 4 + 0]; pa[1] = pacc[it * 4 + 1];
    pa[2] = pacc[it * 4 + 2]; pa[3] = pacc[it * 4 + 3];
    if (h0 != 0) {
      f32x4 old = *(const f32x4*)&prov[pbase + s];
      pa[0] += old[0]; pa[1] += old[1]; pa[2] += old[2]; pa[3] += old[3];
    }
    *(f32x4*)&prov[pbase + s] = pa;
  }
}

// ---------------------------------------------------------------------------
// pv_mfma: Oat[b,t,h*64+d] = sum_s P[t][s] * (Vh+Vl)[s][d], via MFMA with
// P bf16 [rows][4096] and V^T hi/lo planes [1024 d][16384 s]. No LDS.
// 128t x 64d tile, 4 waves each owning 32 t-rows (no redundant P reads).
// ---------------------------------------------------------------------------
__global__ __launch_bounds__(256, 2) void pv_mfma(
    const bf16* __restrict__ P, const bf16* __restrict__ VTh,
    const bf16* __restrict__ VTl, float* __restrict__ Oat,
    int G, int TC, int h0, int tBase) {
  int tid = threadIdx.x;
  int lane = tid & 63, w = tid >> 6;
  int wt0 = w << 5;
  int lrow = lane & 15, lkb = (lane >> 4) << 3;
  int ntt = TC >> 7;
  int bid = blockIdx.x;
  int tt = bid % ntt, bg = bid / ntt;
  int b = bg / G, g = bg % G, h = h0 + g;
  int tl0 = tt << 7;

  f32x4 acc[2][4];
#pragma unroll
  for (int i = 0; i < 2; i++)
#pragma unroll
    for (int j = 0; j < 4; j++) {
      acc[i][j][0] = 0.f; acc[i][j][1] = 0.f;
      acc[i][j][2] = 0.f; acc[i][j][3] = 0.f;
    }

  const bf16* pp = P + (((size_t)(bg * TC + tl0 + wt0 + lrow)) << 12) + lkb;
  const bf16* vph = VTh + (size_t)((h << 6) + lrow) * 16384 + ((size_t)b << 12) + lkb;
  const bf16* vpl = VTl + (size_t)((h << 6) + lrow) * 16384 + ((size_t)b << 12) + lkb;

  for (int k0 = 0; k0 < 4096; k0 += 32) {
    s16x8 pa[2], bvh[4], bvl[4];
#pragma unroll
    for (int nt = 0; nt < 4; ++nt) {
      bvh[nt] = *(const s16x8*)(vph + (size_t)nt * 16 * 16384 + k0);
      bvl[nt] = *(const s16x8*)(vpl + (size_t)nt * 16 * 16384 + k0);
    }
#pragma unroll
    for (int mt = 0; mt < 2; ++mt) pa[mt] = *(const s16x8*)(pp + mt * (16 * 4096) + k0);
#pragma unroll
    for (int mt = 0; mt < 2; ++mt)
#pragma unroll
      for (int nt = 0; nt < 4; ++nt) {
        acc[mt][nt] = mfma16(pa[mt], bvh[nt], acc[mt][nt]);
        acc[mt][nt] = mfma16(pa[mt], bvl[nt], acc[mt][nt]);
      }
  }

  int rbase = (lane >> 4) << 2;
#pragma unroll
  for (int mt = 0; mt < 2; ++mt) {
#pragma unroll
    for (int r = 0; r < 4; ++r) {
      int t = tBase + tl0 + wt0 + mt * 16 + rbase + r;
      size_t obase = (((size_t)((b << 9) + t)) << 10) + (h << 6);
#pragma unroll
      for (int nt = 0; nt < 4; ++nt) Oat[obase + nt * 16 + lrow] = acc[mt][nt][r];
    }
  }
}

// ---------------------------------------------------------------------------
// Fallback GEMM (f32 VALU, verified) + naive attention — only if ws tiny.
// ---------------------------------------------------------------------------
template <typename OUT>
__global__ __launch_bounds__(256, 2) void gemm_f32(
    const float* __restrict__ A, const float* __restrict__ W,
    const float* __restrict__ bias, OUT* __restrict__ out, int M, int mode,
    const int* __restrict__ segids, const float* __restrict__ segemb) {
  __shared__ __align__(16) float AsT[32][132];
  __shared__ __align__(16) float Bs[32][132];

  int tid = threadIdx.x;
  int tx = tid & 15, ty = tid >> 4;
  int nTilesM = M >> 7;
  int bm = blockIdx.x % nTilesM, bn = blockIdx.x / nTilesM;
  int m0 = bm * 128, n0 = bn * 128;

  int sm = tid & 127;
  int skb = (tid >> 7) * 16;

  float acc[8][8];
#pragma unroll
  for (int i = 0; i < 8; i++)
#pragma unroll
    for (int j = 0; j < 8; j++) acc[i][j] = 0.f;

  for (int k0 = 0; k0 < 1024; k0 += 32) {
    {
      const float* src = A + (size_t)(m0 + sm) * 1024 + k0 + skb;
      f32x4 a0 = *(const f32x4*)src;
      f32x4 a1 = *(const f32x4*)(src + 4);
      f32x4 a2 = *(const f32x4*)(src + 8);
      f32x4 a3 = *(const f32x4*)(src + 12);
#pragma unroll
      for (int j = 0; j < 4; j++) {
        AsT[skb + j][sm] = a0[j];
        AsT[skb + 4 + j][sm] = a1[j];
        AsT[skb + 8 + j][sm] = a2[j];
        AsT[skb + 12 + j][sm] = a3[j];
      }
    }
#pragma unroll
    for (int u = tid; u < 512; u += 256) {
      int r = u >> 4, cc = (u & 15) * 8;
      const float* src = W + (size_t)(k0 + r) * 1024 + n0 + cc;
      *(f32x4*)&Bs[r][cc] = *(const f32x4*)src;
      *(f32x4*)&Bs[r][cc + 4] = *(const f32x4*)(src + 4);
    }
    __syncthreads();
#pragma unroll
    for (int kk = 0; kk < 32; kk++) {
      f32x4 av0 = *(const f32x4*)&AsT[kk][ty * 8];
      f32x4 av1 = *(const f32x4*)&AsT[kk][ty * 8 + 4];
      f32x4 bv0 = *(const f32x4*)&Bs[kk][tx * 4];
      f32x4 bv1 = *(const f32x4*)&Bs[kk][64 + tx * 4];
      float av[8] = {av0[0], av0[1], av0[2], av0[3],
                     av1[0], av1[1], av1[2], av1[3]};
#pragma unroll
      for (int i = 0; i < 8; i++) {
#pragma unroll
        for (int j = 0; j < 4; j++) {
          acc[i][j] += av[i] * bv0[j];
          acc[i][4 + j] += av[i] * bv1[j];
        }
      }
    }
    __syncthreads();
  }

#pragma unroll
  for (int i = 0; i < 8; i++) {
    int m = m0 + ty * 8 + i;
    int seg = (mode == 1) ? segids[m] : 0;
#pragma unroll
    for (int jh = 0; jh < 2; jh++) {
#pragma unroll
      for (int j = 0; j < 4; j++) {
        int n = n0 + jh * 64 + tx * 4 + j;
        float v = acc[i][jh * 4 + j] + bias[n];
        if (mode == 1) v += segemb[(size_t)seg * 1024 + n];
        out[(size_t)m * 1024 + n] = (OUT)v;
      }
    }
  }
}

__global__ __launch_bounds__(256) void attn_naive(
    const float* __restrict__ Qp, const float* __restrict__ Kp,
    const bf16* __restrict__ Vp, const int* __restrict__ mask,
    float* __restrict__ Oatt, float* __restrict__ prov) {
  int bt = blockIdx.x;
  int b = bt >> 9, t = bt & 511;
  __shared__ float qs[64];
  __shared__ float sc[4096];
  __shared__ float pacc[4096];
  __shared__ float red[256];
  __shared__ float po[4][64];
  int tid = threadIdx.x, wv = tid >> 6, lane = tid & 63;

  for (int s = tid; s < 4096; s += 256) pacc[s] = 0.f;
  const int* mrow = mask + (b << 12);

  for (int h = 0; h < 16; ++h) {
    __syncthreads();
    if (tid < 64) qs[tid] = Qp[((size_t)(b * 512 + t)) * 1024 + h * 64 + tid];
    __syncthreads();
    for (int s = tid; s < 4096; s += 256) {
      const float* krow = Kp + ((size_t)((b << 12) + s)) * 1024 + h * 64;
      float d = 0.f;
#pragma unroll
      for (int kk = 0; kk < 64; kk += 4) {
        f32x4 kv = *(const f32x4*)(krow + kk);
#pragma unroll
        for (int j = 0; j < 4; ++j) d += qs[kk + j] * kv[j];
      }
      sc[s] = (mrow[s] != 0) ? d * 0.125f : -1.0e9f;
    }
    __syncthreads();
    float mx = -3.0e38f;
    for (int s = tid; s < 4096; s += 256) mx = fmaxf(mx, sc[s]);
    red[tid] = mx;
    __syncthreads();
    for (int off = 128; off; off >>= 1) {
      if (tid < off) red[tid] = fmaxf(red[tid], red[tid + off]);
      __syncthreads();
    }
    float m = red[0];
    __syncthreads();
    float sm = 0.f;
    for (int s = tid; s < 4096; s += 256) {
      float p = __expf(sc[s] - m);
      sc[s] = p;
      sm += p;
    }
    red[tid] = sm;
    __syncthreads();
    for (int off = 128; off; off >>= 1) {
      if (tid < off) red[tid] += red[tid + off];
      __syncthreads();
    }
    float il = 1.0f / red[0];
    for (int s = tid; s < 4096; s += 256) pacc[s] += sc[s] * il * 0.0625f;
    float o = 0.f;
    const bf16* vb = Vp + ((size_t)((b << 12) + wv * 1024)) * 1024 + h * 64 + lane;
    for (int s = 0; s < 1024; ++s) o += sc[wv * 1024 + s] * (float)vb[(size_t)s * 1024];
    po[wv][lane] = o;
    __syncthreads();
    if (tid < 64) {
      float oo = (po[0][tid] + po[1][tid] + po[2][tid] + po[3][tid]) * il;
      Oatt[((size_t)(b * 512 + t)) * 1024 + h * 64 + tid] = oo;
    }
  }
  __syncthreads();
  for (int s = tid; s < 4096; s += 256)
    prov[((size_t)(b * 512 + t)) * 4096 + s] = pacc[s];
}

// ---------------------------------------------------------------------------
extern "C" void kernel_launch(void* const* d_in, const int* in_sizes, int n_in,
                              void* d_out, int out_size, void* d_ws, size_t ws_size,
                              hipStream_t stream) {
  const float* query = (const float*)d_in[0];
  const float* key = (const float*)d_in[1];
  const float* value = (const float*)d_in[2];
  const int* amask = (const int*)d_in[3];
  const int* segid = (const int*)d_in[4];
  const float* Wq = (const float*)d_in[5];
  const float* bq = (const float*)d_in[6];
  const float* Wk = (const float*)d_in[7];
  const float* bk = (const float*)d_in[8];
  const float* Wv = (const float*)d_in[9];
  const float* bv = (const float*)d_in[10];
  const float* Wo = (const float*)d_in[11];
  const float* bo = (const float*)d_in[12];
  const float* semb = (const float*)d_in[13];

  char* ws = (char*)d_ws;
  float* outAtt = (float*)d_out;                  // [4,512,1024] f32
  float* outProv = outAtt + (size_t)2048 * 1024;  // [4,512,4096] f32

  const size_t MB = 1ull << 20;
  const size_t scOff = 144 * MB;
  static const int cand[7][2] = {{16, 512}, {8, 512}, {4, 512}, {2, 512},
                                 {1, 512},  {1, 256}, {1, 128}};
  int G = 0, TC = 0;
  size_t scBytes = 0;
  for (int ci = 0; ci < 7; ++ci) {
    size_t sb = (size_t)4 * cand[ci][0] * cand[ci][1] * 4096 * 4;
    size_t need = scOff + sb + sb / 2;       // Sc + Pb (bf16) mandatory
    size_t scr = scOff + 132 * MB;           // prep scratch high-water
    if (need < scr) need = scr;
    if (need <= ws_size) { G = cand[ci][0]; TC = cand[ci][1]; scBytes = sb; break; }
  }

  if (G > 0) {
    bf16* Qh = (bf16*)ws;                    //  4 MB [2048,1024]
    bf16* Ql = (bf16*)(ws + 4 * MB);         //  4 MB
    bf16* Kh = (bf16*)(ws + 8 * MB);         // 32 MB [16384,1024]
    bf16* Kl = (bf16*)(ws + 40 * MB);        // 32 MB
    bf16* VTh = (bf16*)(ws + 72 * MB);       // 32 MB [1024,16384] (V^T)
    bf16* VTl = (bf16*)(ws + 104 * MB);      // 32 MB
    float* OatF = (float*)(ws + 136 * MB);   //  8 MB
    float* Sc = (float*)(ws + scOff);        // scBytes
    bf16* Pb = (bf16*)(ws + scOff + scBytes);
    // prep scratch inside the (currently dead) Sc region:
    bf16* WTh = (bf16*)(ws + scOff);                  // 2 MB
    bf16* WTl = WTh + (size_t)1024 * 1024;            // 2 MB
    bf16* Ash = (bf16*)(ws + scOff + 4 * MB);         // ≤32 MB
    bf16* Asl = (bf16*)(ws + scOff + 36 * MB);        // ≤32 MB
    float* Vpf = (float*)(ws + scOff + 68 * MB);      // 64 MB

    // Q projection
    split_f32<<<2048, 256, 0, stream>>>(query, Ash, Asl, 524288);
    wtrans<<<256, 256, 0, stream>>>(Wq, WTh, WTl);
    gemm_mfma<2><<<16 * 8, 256, 0, stream>>>(Ash, Asl, WTh, WTl, bq, nullptr,
                                             Qh, Ql, 2048, 0, nullptr, nullptr);
    // K projection (+seg_emb)
    split_f32<<<2048, 256, 0, stream>>>(key, Ash, Asl, 4194304);
    wtrans<<<256, 256, 0, stream>>>(Wk, WTh, WTl);
    gemm_mfma<2><<<128 * 8, 256, 0, stream>>>(Ash, Asl, WTh, WTl, bk, nullptr,
                                              Kh, Kl, 16384, 1, segid, semb);
    // V projection -> f32 -> transposed hi/lo planes
    split_f32<<<2048, 256, 0, stream>>>(value, Ash, Asl, 4194304);
    wtrans<<<256, 256, 0, stream>>>(Wv, WTh, WTl);
    gemm_mfma<0><<<128 * 8, 256, 0, stream>>>(Ash, Asl, WTh, WTl, bv, Vpf,
                                              nullptr, nullptr, 16384, 0,
                                              nullptr, nullptr);
    vtrans<<<4096, 256, 0, stream>>>(Vpf, VTh, VTl);

    int nHC = 16 / G, nTCk = 512 / TC;
    for (int hc = 0; hc < nHC; ++hc) {
      int h0 = hc * G;
      for (int tc = 0; tc < nTCk; ++tc) {
        int tBase = tc * TC;
        qk_mfma<<<4 * G * (TC >> 7) * 32, 256, 0, stream>>>(
            Qh, Ql, Kh, Kl, amask, Sc, G, TC, h0, tBase);
        softmax_prov<1><<<4 * TC, 256, 0, stream>>>(Sc, Pb, outProv, G, TC, h0, tBase);
        pv_mfma<<<4 * G * (TC >> 7), 256, 0, stream>>>(Pb, VTh, VTl, OatF, G,
                                                       TC, h0, tBase);
      }
    }
    // O projection
    split_f32<<<2048, 256, 0, stream>>>(OatF, Ash, Asl, 524288);
    wtrans<<<256, 256, 0, stream>>>(Wo, WTh, WTl);
    gemm_mfma<0><<<16 * 8, 256, 0, stream>>>(Ash, Asl, WTh, WTl, bo, outAtt,
                                             nullptr, nullptr, 2048, 0,
                                             nullptr, nullptr);
  } else {
    // Fallback: original verified path (needs 112 MB).
    float* Qp = (float*)ws;                   // 8 MB
    float* Kp = (float*)(ws + 8 * MB);        // 64 MB
    bf16* Vp = (bf16*)(ws + 72 * MB);         // 32 MB
    float* OatF = (float*)(ws + 104 * MB);    // 8 MB

    gemm_f32<float><<<16 * 8, 256, 0, stream>>>(query, Wq, bq, Qp, 2048, 0, nullptr, nullptr);
    gemm_f32<float><<<128 * 8, 256, 0, stream>>>(key, Wk, bk, Kp, 16384, 1, segid, semb);
    gemm_f32<bf16><<<128 * 8, 256, 0, stream>>>(value, Wv, bv, Vp, 16384, 0, nullptr, nullptr);
    attn_naive<<<2048, 256, 0, stream>>>(Qp, Kp, Vp, amask, OatF, outProv);
    gemm_f32<float><<<16 * 8, 256, 0, stream>>>(OatF, Wo, bo, outAtt, 2048, 0, nullptr, nullptr);
  }
}